// Round 2
// baseline (841.676 us; speedup 1.0000x reference)
//
#include <hip/hip_runtime.h>

typedef __attribute__((ext_vector_type(4))) float floatx4;
typedef __attribute__((ext_vector_type(8))) short shortx8;
typedef __attribute__((ext_vector_type(4))) int intx4;

#define DEVI static __device__ __forceinline__

constexpr int NN = 20000;   // nodes
constexpr int NE = 640000;  // edges
// workspace layout (bytes): bf16 transposed weights first, f32 agg after
constexpr size_t W1T_OFF = 0;                         // 128x352 bf16
constexpr size_t W2T_OFF = W1T_OFF + 128 * 352 * 2;   // 128x128
constexpr size_t WGT_OFF = W2T_OFF + 128 * 128 * 2;   // 16x128
constexpr size_t U1T_OFF = WGT_OFF + 16 * 128 * 2;    // 128x288
constexpr size_t U2T_OFF = U1T_OFF + 128 * 288 * 2;   // 128x128
constexpr size_t UGT_OFF = U2T_OFF + 128 * 128 * 2;   // 16x128
constexpr size_t AGG_S_OFF = 262144;                  // 20000*128 f32
constexpr size_t AGG_V_OFF = AGG_S_OFF + (size_t)NN * 128 * 4;  // 20000*48 f32
constexpr size_t AGG_BYTES = (size_t)NN * 128 * 4 + (size_t)NN * 48 * 4;

DEVI float bf2f(short h) {
  union { unsigned u; float f; } c;
  c.u = ((unsigned)(unsigned short)h) << 16;
  return c.f;
}
DEVI short f2bf(float f) {  // round-to-nearest-even
  union { float f; unsigned u; } c; c.f = f;
  unsigned x = c.u;
  return (short)((x + 0x7fffu + ((x >> 16) & 1u)) >> 16);
}
DEVI float sigm(float x) { return 1.0f / (1.0f + __expf(-x)); }

DEVI floatx4 mfma16(shortx8 a, shortx8 b, floatx4 c) {
  return __builtin_amdgcn_mfma_f32_16x16x32_bf16(a, b, c, 0, 0, 0);
}

// ---------------- weight transpose+cast prep ----------------
// f32 [in,out] global -> bf16 [out][in] rows in ws (MFMA B-fragments
// become 8 contiguous bf16: lane n=L%16 holds B[k=quad*8+j][n]).
__global__ void gvp_prep(const float* __restrict__ mW1, const float* __restrict__ mW2,
                         const float* __restrict__ mWg, const float* __restrict__ uW1,
                         const float* __restrict__ uW2, const float* __restrict__ uWg,
                         short* __restrict__ w1t, short* __restrict__ w2t,
                         short* __restrict__ wgt, short* __restrict__ u1t,
                         short* __restrict__ u2t, short* __restrict__ ugt) {
  int i = blockIdx.x * 256 + threadIdx.x;
  if (i < 45056) { int n = i / 352, k = i % 352; w1t[i] = (k < 322) ? f2bf(mW1[k * 128 + n]) : (short)0; return; }
  i -= 45056;
  if (i < 16384) { int n = i >> 7, k = i & 127; w2t[i] = f2bf(mW2[k * 128 + n]); return; }
  i -= 16384;
  if (i < 2048) { int g = i >> 7, k = i & 127; wgt[i] = f2bf(mWg[k * 16 + g]); return; }
  i -= 2048;
  if (i < 36864) { int n = i / 288, k = i % 288; u1t[i] = f2bf(uW1[k * 128 + n]); return; }
  i -= 36864;
  if (i < 16384) { int n = i >> 7, k = i & 127; u2t[i] = f2bf(uW2[k * 128 + n]); return; }
  i -= 16384;
  if (i < 2048) { int g = i >> 7, k = i & 127; ugt[i] = f2bf(uWg[k * 16 + g]); return; }
}

// ---------------- edge message kernel ----------------
// 64 edges/block, 256 threads (4 waves). X tile [64][352] bf16 in LDS:
// cols 0..127 s[src], 128..255 s[dst], 256..287 edge_s, 288 |edge_v|,
// 289..320 vn(src,dst), 321 |edge_v|, 322..351 zero pad (W1t pad rows zero).
__global__ __launch_bounds__(256) void gvp_edge(
    const float* __restrict__ s, const float* __restrict__ v,
    const int* __restrict__ eidx, const float* __restrict__ es,
    const float* __restrict__ ev, const short* __restrict__ w1t,
    const short* __restrict__ w2t, const short* __restrict__ wgt,
    const float* __restrict__ b1, const float* __restrict__ b2,
    const float* __restrict__ wvw, const float* __restrict__ bg,
    float* __restrict__ agg_s, float* __restrict__ agg_v) {
  __shared__ __align__(16) short lx[64 * 352];  // reused: lh[64][136] + lmv f32
  __shared__ __align__(16) short lw[128 * 32];  // weight chunk / Wg[16][128]
  __shared__ int lsrc[64];
  __shared__ int ldst[64];

  const int tid = threadIdx.x;
  const int wid = tid >> 6;
  const int lane = tid & 63;
  const int quad = lane >> 4;
  const int l16 = lane & 15;
  const int e0 = blockIdx.x * 64;

  if (tid < 64) lsrc[tid] = eidx[e0 + tid];
  else if (tid < 128) ldst[tid - 64] = eidx[NE + e0 + (tid - 64)];
  __syncthreads();

  // ---- build X (f32 gather -> bf16) ----
#pragma unroll
  for (int i = 0; i < 8; i++) {  // s[src], s[dst]: 64 rows x 32 8-elem chunks
    int idx = tid + i * 256;
    int r = idx >> 5, c = idx & 31;
    int node = (c < 16) ? lsrc[r] : ldst[r];
    int cc = (c & 15) * 8;
    const float* sp = s + (size_t)node * 128 + cc;
    floatx4 f0 = *(const floatx4*)sp;
    floatx4 f1 = *(const floatx4*)(sp + 4);
    union { short sh[8]; intx4 v4; } u;
#pragma unroll
    for (int j = 0; j < 4; j++) { u.sh[j] = f2bf(f0[j]); u.sh[4 + j] = f2bf(f1[j]); }
    *(intx4*)(lx + r * 352 + (c < 16 ? 0 : 128) + cc) = u.v4;
  }
  {  // edge_s + zero pad
    int r = tid >> 2, q = tid & 3;
    const float* ep = es + (size_t)(e0 + r) * 32 + q * 8;
    floatx4 f0 = *(const floatx4*)ep;
    floatx4 f1 = *(const floatx4*)(ep + 4);
    union { short sh[8]; intx4 v4; } u;
#pragma unroll
    for (int j = 0; j < 4; j++) { u.sh[j] = f2bf(f0[j]); u.sh[4 + j] = f2bf(f1[j]); }
    *(intx4*)(lx + r * 352 + 256 + q * 8) = u.v4;
    intx4 z = {0, 0, 0, 0};
    if (q < 3) *(intx4*)(lx + r * 352 + 328 + q * 8) = z;
    else { for (int t = 322; t < 328; t++) lx[r * 352 + t] = 0; }
  }
  {  // vector norms
    int r = tid >> 2, p = tid & 3;
    int node = (p < 2) ? lsrc[r] : ldst[r];
    int w0 = (p & 1) * 8;
    const float* vp = v + (size_t)node * 48 + w0 * 3;
#pragma unroll
    for (int w = 0; w < 8; w++) {
      float x = vp[w * 3], y = vp[w * 3 + 1], z = vp[w * 3 + 2];
      lx[r * 352 + 289 + (p >> 1) * 16 + w0 + w] = f2bf(sqrtf(fmaxf(x * x + y * y + z * z, 1e-8f)));
    }
    if (p == 3) {
      const float* evp = ev + (size_t)(e0 + r) * 3;
      float x = evp[0], y = evp[1], z = evp[2];
      short lb = f2bf(sqrtf(fmaxf(x * x + y * y + z * z, 1e-8f)));
      lx[r * 352 + 288] = lb;
      lx[r * 352 + 321] = lb;
    }
  }

  // ---- GEMM1: h = X @ W1 (K=352 incl pad, 11 chunks) ----
  const int m0 = (wid & 1) * 32;
  const int n0 = (wid >> 1) * 64;
  floatx4 acc[2][4] = {};
  for (int kc = 0; kc < 11; kc++) {
    __syncthreads();
#pragma unroll
    for (int i = 0; i < 2; i++) {
      int idx = tid + i * 256;
      int n = idx >> 2, q = idx & 3;
      *(intx4*)(lw + n * 32 + q * 8) = *(const intx4*)(w1t + (size_t)n * 352 + kc * 32 + q * 8);
    }
    __syncthreads();
    shortx8 a0 = *(const shortx8*)(lx + (m0 + l16) * 352 + kc * 32 + quad * 8);
    shortx8 a1 = *(const shortx8*)(lx + (m0 + 16 + l16) * 352 + kc * 32 + quad * 8);
#pragma unroll
    for (int ni = 0; ni < 4; ni++) {
      shortx8 b = *(const shortx8*)(lw + (n0 + ni * 16 + l16) * 32 + quad * 8);
      acc[0][ni] = mfma16(a0, b, acc[0][ni]);
      acc[1][ni] = mfma16(a1, b, acc[1][ni]);
    }
  }
  __syncthreads();

  // ---- silu(h+b1) -> lh bf16 (stride 136) ----
  short* lh = lx;
#pragma unroll
  for (int mi = 0; mi < 2; mi++)
#pragma unroll
    for (int ni = 0; ni < 4; ni++)
#pragma unroll
      for (int i = 0; i < 4; i++) {
        int row = m0 + mi * 16 + quad * 4 + i;
        int col = n0 + ni * 16 + l16;
        float h = acc[mi][ni][i] + b1[col];
        lh[row * 136 + col] = f2bf(h * sigm(h));
      }

  // ---- GEMM2: s2 = silu(h) @ W2 (K=128, 4 chunks) ----
  floatx4 acc2[2][4] = {};
  for (int kc = 0; kc < 4; kc++) {
    __syncthreads();
#pragma unroll
    for (int i = 0; i < 2; i++) {
      int idx = tid + i * 256;
      int n = idx >> 2, q = idx & 3;
      *(intx4*)(lw + n * 32 + q * 8) = *(const intx4*)(w2t + (size_t)n * 128 + kc * 32 + q * 8);
    }
    __syncthreads();
    shortx8 a0 = *(const shortx8*)(lh + (m0 + l16) * 136 + kc * 32 + quad * 8);
    shortx8 a1 = *(const shortx8*)(lh + (m0 + 16 + l16) * 136 + kc * 32 + quad * 8);
#pragma unroll
    for (int ni = 0; ni < 4; ni++) {
      shortx8 b = *(const shortx8*)(lw + (n0 + ni * 16 + l16) * 32 + quad * 8);
      acc2[0][ni] = mfma16(a0, b, acc2[0][ni]);
      acc2[1][ni] = mfma16(a1, b, acc2[1][ni]);
    }
  }
  __syncthreads();

  // ---- s2 epilogue: bf16 to lh (gate GEMM input) + f32 atomic scatter ----
#pragma unroll
  for (int mi = 0; mi < 2; mi++)
#pragma unroll
    for (int ni = 0; ni < 4; ni++)
#pragma unroll
      for (int i = 0; i < 4; i++) {
        int row = m0 + mi * 16 + quad * 4 + i;
        int col = n0 + ni * 16 + l16;
        float t = acc2[mi][ni][i] + b2[col];
        lh[row * 136 + col] = f2bf(t);
        atomicAdd(agg_s + (size_t)ldst[row] * 128 + col, t);
      }
  __syncthreads();

  // ---- stage Wg [16][128] bf16 + per-wave m_v_in tile [16][100] f32 ----
  {
    int n = tid >> 4, q = tid & 15;
    *(intx4*)(lw + n * 128 + q * 8) = *(const intx4*)(wgt + n * 128 + q * 8);
  }
  float* lmvf = (float*)((char*)lx + 17408) + wid * 1600;  // 16 edges x 100 f32
  {
    int e = lane >> 2, p = lane & 3;
    int er = wid * 16 + e;
    int node = (p < 2) ? lsrc[er] : ldst[er];
    const floatx4* sp = (const floatx4*)(v + (size_t)node * 48 + (p & 1) * 24);
    floatx4* dp = (floatx4*)(lmvf + e * 100 + p * 24);
#pragma unroll
    for (int j = 0; j < 6; j++) dp[j] = sp[j];
    if (p == 3) {
      const float* evp = ev + (size_t)(e0 + er) * 3;
      lmvf[e * 100 + 96] = evp[0];
      lmvf[e * 100 + 97] = evp[1];
      lmvf[e * 100 + 98] = evp[2];
    }
  }
  __syncthreads();

  // ---- GEMM3: gate logits = s2 @ Wg (K=128, N=16); wave owns 16 edges ----
  floatx4 acc3 = {};
#pragma unroll
  for (int kc = 0; kc < 4; kc++) {
    shortx8 a = *(const shortx8*)(lh + (wid * 16 + l16) * 136 + kc * 32 + quad * 8);
    shortx8 b = *(const shortx8*)(lw + l16 * 128 + kc * 32 + quad * 8);
    acc3 = mfma16(a, b, acc3);
  }

  // ---- v_proj (f32) + gated atomic scatter; lane: w=l16, edges quad*4+i ----
  float vm[4][3] = {};
  for (int j = 0; j < 33; j++) {
    float wj = wvw[j * 16 + l16];
#pragma unroll
    for (int i = 0; i < 4; i++) {
      int e = quad * 4 + i;
      vm[i][0] += wj * lmvf[e * 100 + j * 3 + 0];
      vm[i][1] += wj * lmvf[e * 100 + j * 3 + 1];
      vm[i][2] += wj * lmvf[e * 100 + j * 3 + 2];
    }
  }
#pragma unroll
  for (int i = 0; i < 4; i++) {
    int er = wid * 16 + quad * 4 + i;
    int d = ldst[er];
    float g = sigm(acc3[i] + bg[l16]);
    float* ap = agg_v + (size_t)d * 48 + l16 * 3;
    atomicAdd(ap + 0, g * vm[i][0]);
    atomicAdd(ap + 1, g * vm[i][1]);
    atomicAdd(ap + 2, g * vm[i][2]);
  }
}

// ---------------- node update kernel ----------------
// 64 nodes/block; wave owns 16 full rows (LayerNorm reduction).
__global__ __launch_bounds__(256) void gvp_node(
    const float* __restrict__ s, const float* __restrict__ v,
    const float* __restrict__ agg_s, const float* __restrict__ agg_v,
    const short* __restrict__ u1t, const short* __restrict__ u2t,
    const short* __restrict__ ugt, const float* __restrict__ b1,
    const float* __restrict__ b2, const float* __restrict__ uwv,
    const float* __restrict__ bg, const float* __restrict__ lng,
    const float* __restrict__ lnb, float* __restrict__ out_s,
    float* __restrict__ out_v) {
  __shared__ __align__(16) short lx[64 * 352];  // X2 [64][288] + lh + lmv f32
  __shared__ __align__(16) short lw[128 * 32];
  const int tid = threadIdx.x;
  const int wid = tid >> 6;
  const int lane = tid & 63;
  const int quad = lane >> 4;
  const int l16 = lane & 15;
  const int nb0 = blockIdx.x * 64;

  // ---- build X2 [64][288] bf16: s | agg_s | vn(32) ----
  intx4 z4 = {0, 0, 0, 0};
#pragma unroll
  for (int i = 0; i < 4; i++) {
    int idx = tid + i * 256;
    int r = idx >> 4, cc = (idx & 15) * 8;
    int node = nb0 + r;
    union { short sh[8]; intx4 v4; } u;
    u.v4 = z4;
    if (node < NN) {
      const float* sp = s + (size_t)node * 128 + cc;
      floatx4 f0 = *(const floatx4*)sp;
      floatx4 f1 = *(const floatx4*)(sp + 4);
#pragma unroll
      for (int j = 0; j < 4; j++) { u.sh[j] = f2bf(f0[j]); u.sh[4 + j] = f2bf(f1[j]); }
    }
    *(intx4*)(lx + r * 288 + cc) = u.v4;
  }
#pragma unroll
  for (int i = 0; i < 4; i++) {
    int idx = tid + i * 256;
    int r = idx >> 4, cc = (idx & 15) * 8;
    int node = nb0 + r;
    union { short sh[8]; intx4 v4; } u;
    u.v4 = z4;
    if (node < NN) {
      const float* ap = agg_s + (size_t)node * 128 + cc;
      floatx4 f0 = *(const floatx4*)ap;
      floatx4 f1 = *(const floatx4*)(ap + 4);
#pragma unroll
      for (int j = 0; j < 4; j++) { u.sh[j] = f2bf(f0[j]); u.sh[4 + j] = f2bf(f1[j]); }
    }
    *(intx4*)(lx + r * 288 + 128 + cc) = u.v4;
  }
  {
    int r = tid >> 2, p = tid & 3;
    int node = nb0 + r;
    int w0 = (p & 1) * 8;
    const float* vp = (p < 2) ? (v + (size_t)node * 48 + w0 * 3)
                              : (agg_v + (size_t)node * 48 + w0 * 3);
    int cbase = (p < 2) ? 256 : 272;
#pragma unroll
    for (int w = 0; w < 8; w++) {
      float nv = 0.f;
      if (node < NN) {
        float x = vp[w * 3], y = vp[w * 3 + 1], zz = vp[w * 3 + 2];
        nv = sqrtf(fmaxf(x * x + y * y + zz * zz, 1e-8f));
      }
      lx[r * 288 + cbase + w0 + w] = f2bf(nv);
    }
  }

  // ---- GEMM1 (K=288, 9 chunks), wave = 16 rows x 128 cols ----
  floatx4 acc[8] = {};
  for (int kc = 0; kc < 9; kc++) {
    __syncthreads();
#pragma unroll
    for (int i = 0; i < 2; i++) {
      int idx = tid + i * 256;
      int n = idx >> 2, q = idx & 3;
      *(intx4*)(lw + n * 32 + q * 8) = *(const intx4*)(u1t + (size_t)n * 288 + kc * 32 + q * 8);
    }
    __syncthreads();
    shortx8 a = *(const shortx8*)(lx + (wid * 16 + l16) * 288 + kc * 32 + quad * 8);
#pragma unroll
    for (int nt = 0; nt < 8; nt++) {
      shortx8 b = *(const shortx8*)(lw + (nt * 16 + l16) * 32 + quad * 8);
      acc[nt] = mfma16(a, b, acc[nt]);
    }
  }
  __syncthreads();
  short* lh = lx;
#pragma unroll
  for (int nt = 0; nt < 8; nt++)
#pragma unroll
    for (int i = 0; i < 4; i++) {
      int row = wid * 16 + quad * 4 + i;
      int col = nt * 16 + l16;
      float h = acc[nt][i] + b1[col];
      lh[row * 136 + col] = f2bf(h * sigm(h));
    }

  // ---- GEMM2 (K=128) ----
  floatx4 acc2[8] = {};
  for (int kc = 0; kc < 4; kc++) {
    __syncthreads();
#pragma unroll
    for (int i = 0; i < 2; i++) {
      int idx = tid + i * 256;
      int n = idx >> 2, q = idx & 3;
      *(intx4*)(lw + n * 32 + q * 8) = *(const intx4*)(u2t + (size_t)n * 128 + kc * 32 + q * 8);
    }
    __syncthreads();
    shortx8 a = *(const shortx8*)(lh + (wid * 16 + l16) * 136 + kc * 32 + quad * 8);
#pragma unroll
    for (int nt = 0; nt < 8; nt++) {
      shortx8 b = *(const shortx8*)(lw + (nt * 16 + l16) * 32 + quad * 8);
      acc2[nt] = mfma16(a, b, acc2[nt]);
    }
  }
  __syncthreads();

  // ---- epilogue: ds -> lh bf16 (gate input); t = s + ds in acc2 (f32) ----
#pragma unroll
  for (int nt = 0; nt < 8; nt++)
#pragma unroll
    for (int i = 0; i < 4; i++) {
      int row = wid * 16 + quad * 4 + i;
      int col = nt * 16 + l16;
      int node = nb0 + row;
      float ds = acc2[nt][i] + b2[col];
      lh[row * 136 + col] = f2bf(ds);
      float sv = (node < NN) ? s[(size_t)node * 128 + col] : 0.f;
      acc2[nt][i] = sv + ds;
    }

  // ---- LayerNorm over 128 cols (8 local + 16-lane shuffle reduce) ----
#pragma unroll
  for (int i = 0; i < 4; i++) {
    float sum = 0.f, sq = 0.f;
#pragma unroll
    for (int nt = 0; nt < 8; nt++) { float t = acc2[nt][i]; sum += t; sq += t * t; }
    for (int off = 1; off < 16; off <<= 1) {
      sum += __shfl_xor(sum, off);
      sq += __shfl_xor(sq, off);
    }
    float mean = sum * (1.f / 128.f);
    float var = sq * (1.f / 128.f) - mean * mean;
    float inv = rsqrtf(fmaxf(var, 0.f) + 1e-5f);
    int row = wid * 16 + quad * 4 + i;
    int node = nb0 + row;
    if (node < NN) {
#pragma unroll
      for (int nt = 0; nt < 8; nt++) {
        int col = nt * 16 + l16;
        float o = (acc2[nt][i] - mean) * inv * lng[col] + lnb[col];
        out_s[(size_t)node * 128 + col] = o;
      }
    }
  }
  __syncthreads();

  // ---- stage Ug [16][128] bf16 + per-wave u_v_in tile [16][100] f32 ----
  {
    int n = tid >> 4, q = tid & 15;
    *(intx4*)(lw + n * 128 + q * 8) = *(const intx4*)(ugt + n * 128 + q * 8);
  }
  float* lmvf = (float*)((char*)lx + 17408) + wid * 1600;
  {
    int e = lane >> 2, p = lane & 3;
    int node = nb0 + wid * 16 + e;
    const float* src = (p < 2) ? (v + (size_t)node * 48 + p * 24)
                               : (agg_v + (size_t)node * 48 + (p - 2) * 24);
    floatx4* dp = (floatx4*)(lmvf + e * 100 + p * 24);
    if (node < NN) {
      const floatx4* sp = (const floatx4*)src;
#pragma unroll
      for (int j = 0; j < 6; j++) dp[j] = sp[j];
    } else {
      floatx4 zf = {0.f, 0.f, 0.f, 0.f};
#pragma unroll
      for (int j = 0; j < 6; j++) dp[j] = zf;
    }
  }
  __syncthreads();

  // ---- GEMM3: gate logits = ds @ Ug ----
  floatx4 acc3 = {};
#pragma unroll
  for (int kc = 0; kc < 4; kc++) {
    shortx8 a = *(const shortx8*)(lh + (wid * 16 + l16) * 136 + kc * 32 + quad * 8);
    shortx8 b = *(const shortx8*)(lw + l16 * 128 + kc * 32 + quad * 8);
    acc3 = mfma16(a, b, acc3);
  }

  // ---- dv (f32) + residual store ----
  float vm[4][3] = {};
  for (int j = 0; j < 32; j++) {
    float wj = uwv[j * 16 + l16];
#pragma unroll
    for (int i = 0; i < 4; i++) {
      int e = quad * 4 + i;
      vm[i][0] += wj * lmvf[e * 100 + j * 3 + 0];
      vm[i][1] += wj * lmvf[e * 100 + j * 3 + 1];
      vm[i][2] += wj * lmvf[e * 100 + j * 3 + 2];
    }
  }
#pragma unroll
  for (int i = 0; i < 4; i++) {
    int row = wid * 16 + quad * 4 + i;
    int node = nb0 + row;
    if (node < NN) {
      float g = sigm(acc3[i] + bg[l16]);
      size_t base = (size_t)node * 48 + l16 * 3;
      out_v[base + 0] = v[base + 0] + g * vm[i][0];
      out_v[base + 1] = v[base + 1] + g * vm[i][1];
      out_v[base + 2] = v[base + 2] + g * vm[i][2];
    }
  }
}

extern "C" void kernel_launch(void* const* d_in, const int* in_sizes, int n_in,
                              void* d_out, int out_size, void* d_ws, size_t ws_size,
                              hipStream_t stream) {
  const float* s = (const float*)d_in[0];
  const float* v = (const float*)d_in[1];
  const int* eidx = (const int*)d_in[2];
  const float* es = (const float*)d_in[3];
  const float* ev = (const float*)d_in[4];
  const float* mW1 = (const float*)d_in[5];
  const float* mb1 = (const float*)d_in[6];
  const float* mW2 = (const float*)d_in[7];
  const float* mb2 = (const float*)d_in[8];
  const float* mWv = (const float*)d_in[9];
  const float* mWg = (const float*)d_in[10];
  const float* mbg = (const float*)d_in[11];
  const float* uW1 = (const float*)d_in[12];
  const float* ub1 = (const float*)d_in[13];
  const float* uW2 = (const float*)d_in[14];
  const float* ub2 = (const float*)d_in[15];
  const float* uWv = (const float*)d_in[16];
  const float* uWg = (const float*)d_in[17];
  const float* ubg = (const float*)d_in[18];
  const float* lng = (const float*)d_in[19];
  const float* lnb = (const float*)d_in[20];

  char* ws = (char*)d_ws;
  short* w1t = (short*)(ws + W1T_OFF);
  short* w2t = (short*)(ws + W2T_OFF);
  short* wgt = (short*)(ws + WGT_OFF);
  short* u1t = (short*)(ws + U1T_OFF);
  short* u2t = (short*)(ws + U2T_OFF);
  short* ugt = (short*)(ws + UGT_OFF);
  float* agg_s = (float*)(ws + AGG_S_OFF);
  float* agg_v = (float*)(ws + AGG_V_OFF);

  hipMemsetAsync(ws + AGG_S_OFF, 0, AGG_BYTES, stream);
  gvp_prep<<<464, 256, 0, stream>>>(mW1, mW2, mWg, uW1, uW2, uWg,
                                    w1t, w2t, wgt, u1t, u2t, ugt);
  gvp_edge<<<NE / 64, 256, 0, stream>>>(s, v, eidx, es, ev, w1t, w2t, wgt,
                                        mb1, mb2, mWv, mbg, agg_s, agg_v);
  gvp_node<<<(NN + 63) / 64, 256, 0, stream>>>(s, v, agg_s, agg_v, u1t, u2t, ugt,
                                               ub1, ub2, uWv, ubg, lng, lnb,
                                               (float*)d_out,
                                               (float*)d_out + (size_t)NN * 128);
}

// Round 3
// 790.719 us; speedup vs baseline: 1.0644x; 1.0644x over previous
//
#include <hip/hip_runtime.h>

typedef __attribute__((ext_vector_type(4))) float floatx4;
typedef __attribute__((ext_vector_type(8))) short shortx8;
typedef __attribute__((ext_vector_type(4))) int intx4;

#define DEVI static __device__ __forceinline__

constexpr int NN = 20000;   // nodes
constexpr int NE = 640000;  // edges

// ---- workspace layout (bytes) ----
constexpr size_t W1ET_OFF = 0;                      // [128][32] bf16 (edge_s rows of W1, out-major)
constexpr size_t WLEN_OFF = 8192;                   // [128] f32 (W1 row 288 + row 321)
constexpr size_t WCAT_OFF = 8704;                   // [256][160] bf16 (A_src|A_dst weights)
constexpr size_t W2T_OFF  = 90624;                  // [128][128] bf16
constexpr size_t WGT_OFF  = 123392;                 // [16][128] bf16
constexpr size_t U1T_OFF  = 127488;                 // [128][288] bf16
constexpr size_t U2T_OFF  = 201216;                 // [128][128] bf16
constexpr size_t UGT_OFF  = 233984;                 // [16][128] bf16
constexpr size_t ASRC_OFF = 238080;                 // [N][128] f32 (col-transposed: [node][j16][t8])
constexpr size_t ADST_OFF = ASRC_OFF + (size_t)NN * 128 * 4;
constexpr size_t BSRC_OFF = ADST_OFF + (size_t)NN * 128 * 4;   // [N][16][3] f32
constexpr size_t BDST_OFF = BSRC_OFF + (size_t)NN * 48 * 4;
constexpr size_t AGG_S_OFF = BDST_OFF + (size_t)NN * 48 * 4;   // [N][128] f32
constexpr size_t AGG_V_OFF = AGG_S_OFF + (size_t)NN * 128 * 4; // [N][16][3] f32
constexpr size_t AGG_BYTES = (size_t)NN * 128 * 4 + (size_t)NN * 48 * 4;

DEVI float bf2f(short h) {
  union { unsigned u; float f; } c;
  c.u = ((unsigned)(unsigned short)h) << 16;
  return c.f;
}
DEVI short f2bf(float f) {  // round-to-nearest-even
  union { float f; unsigned u; } c; c.f = f;
  unsigned x = c.u;
  return (short)((x + 0x7fffu + ((x >> 16) & 1u)) >> 16);
}
DEVI float sigm(float x) { return 1.0f / (1.0f + __expf(-x)); }

DEVI floatx4 mfma16(shortx8 a, shortx8 b, floatx4 c) {
  return __builtin_amdgcn_mfma_f32_16x16x32_bf16(a, b, c, 0, 0, 0);
}

// ---------------- weight transform prep ----------------
// m_s_in layout: [s_src 0:128 | s_dst 128:256 | edge_s 256:288 | len 288 |
//                 vn_src 289:305 | vn_dst 305:321 | len 321]
__global__ void gvp_prep(const float* __restrict__ mW1, const float* __restrict__ mW2,
                         const float* __restrict__ mWg, const float* __restrict__ uW1,
                         const float* __restrict__ uW2, const float* __restrict__ uWg,
                         short* __restrict__ w1et, float* __restrict__ wlen,
                         short* __restrict__ wcat, short* __restrict__ w2t,
                         short* __restrict__ wgt, short* __restrict__ u1t,
                         short* __restrict__ u2t, short* __restrict__ ugt) {
  int i = blockIdx.x * 256 + threadIdx.x;
  if (i < 4096) { int n = i >> 5, k = i & 31; w1et[i] = f2bf(mW1[(256 + k) * 128 + n]); return; }
  i -= 4096;
  if (i < 128) { wlen[i] = mW1[288 * 128 + i] + mW1[321 * 128 + i]; return; }
  i -= 128;
  if (i < 40960) {  // wcat [256][160]
    int n = i / 160, k = i % 160;
    float val = 0.f;
    if (n < 128) {
      if (k < 128) val = mW1[k * 128 + n];
      else if (k < 144) val = mW1[(161 + k) * 128 + n];   // 289 + (k-128)
    } else {
      int n2 = n - 128;
      if (k < 128) val = mW1[(128 + k) * 128 + n2];
      else if (k < 144) val = mW1[(177 + k) * 128 + n2];  // 305 + (k-128)
    }
    wcat[i] = f2bf(val);
    return;
  }
  i -= 40960;
  if (i < 16384) { int n = i >> 7, k = i & 127; w2t[i] = f2bf(mW2[k * 128 + n]); return; }
  i -= 16384;
  if (i < 2048) { int g = i >> 7, k = i & 127; wgt[i] = f2bf(mWg[k * 16 + g]); return; }
  i -= 2048;
  if (i < 36864) { int n = i / 288, k = i % 288; u1t[i] = f2bf(uW1[k * 128 + n]); return; }
  i -= 36864;
  if (i < 16384) { int n = i >> 7, k = i & 127; u2t[i] = f2bf(uW2[k * 128 + n]); return; }
  i -= 16384;
  if (i < 2048) { int g = i >> 7, k = i & 127; ugt[i] = f2bf(uWg[k * 16 + g]); return; }
}

// ---------------- per-node precompute ----------------
// A_src[n] = [s,vn]@W1a + b1, A_dst[n] = [s,vn]@W1b  (f32, col-transposed
// layout A[node][j=col%16][t=col/16] so edge gathers are 2 contiguous x4).
// B_src/B_dst[n][w][c] = sum_j v[n][j][c] * Wv[(0|16)+j][w]  (exact f32).
__global__ __launch_bounds__(256) void gvp_nodepre(
    const float* __restrict__ s, const float* __restrict__ v,
    const short* __restrict__ wcat, const float* __restrict__ b1,
    const float* __restrict__ wv, float* __restrict__ Asrc,
    float* __restrict__ Adst, float* __restrict__ Bsrc, float* __restrict__ Bdst) {
  __shared__ __align__(16) short lx[64 * 160];
  __shared__ __align__(16) short lw[256 * 32];
  const int tid = threadIdx.x;
  const int wid = tid >> 6;
  const int lane = tid & 63;
  const int quad = lane >> 4;
  const int l16 = lane & 15;
  const int nb0 = blockIdx.x * 64;

  intx4 z4 = {0, 0, 0, 0};
#pragma unroll
  for (int i = 0; i < 4; i++) {
    int idx = tid + i * 256;
    int r = idx >> 4, cc = (idx & 15) * 8;
    int node = nb0 + r;
    union { short sh[8]; intx4 v4; } u;
    u.v4 = z4;
    if (node < NN) {
      const float* sp = s + (size_t)node * 128 + cc;
      floatx4 f0 = *(const floatx4*)sp, f1 = *(const floatx4*)(sp + 4);
#pragma unroll
      for (int j = 0; j < 4; j++) { u.sh[j] = f2bf(f0[j]); u.sh[4 + j] = f2bf(f1[j]); }
    }
    *(intx4*)(lx + r * 160 + cc) = u.v4;
  }
  if (tid < 64) {
    int node = nb0 + tid;
    union { short sh[16]; intx4 v4[2]; } u;
#pragma unroll
    for (int j = 0; j < 16; j++) {
      float nv = 0.f;
      if (node < NN) {
        const float* vp = v + (size_t)node * 48 + j * 3;
        nv = sqrtf(fmaxf(vp[0] * vp[0] + vp[1] * vp[1] + vp[2] * vp[2], 1e-8f));
      }
      u.sh[j] = f2bf(nv);
    }
    *(intx4*)(lx + tid * 160 + 128) = u.v4[0];
    *(intx4*)(lx + tid * 160 + 136) = u.v4[1];
    *(intx4*)(lx + tid * 160 + 144) = z4;
    *(intx4*)(lx + tid * 160 + 152) = z4;
  }

  floatx4 acc[16] = {};
  for (int kc = 0; kc < 5; kc++) {
    __syncthreads();
#pragma unroll
    for (int i = 0; i < 4; i++) {
      int idx = tid + i * 256;
      int n = idx >> 2, q = idx & 3;
      *(intx4*)(lw + n * 32 + q * 8) = *(const intx4*)(wcat + (size_t)n * 160 + kc * 32 + q * 8);
    }
    __syncthreads();
    shortx8 a = *(const shortx8*)(lx + (wid * 16 + l16) * 160 + kc * 32 + quad * 8);
#pragma unroll
    for (int nt = 0; nt < 16; nt++) {
      shortx8 b = *(const shortx8*)(lw + (nt * 16 + l16) * 32 + quad * 8);
      acc[nt] = mfma16(a, b, acc[nt]);
    }
  }

  float b1v[8];
#pragma unroll
  for (int nt = 0; nt < 8; nt++) b1v[nt] = b1[nt * 16 + l16];
#pragma unroll
  for (int i = 0; i < 4; i++) {
    int row = wid * 16 + quad * 4 + i;
    int node = nb0 + row;
    if (node < NN) {
      floatx4 p0 = {acc[0][i] + b1v[0], acc[1][i] + b1v[1], acc[2][i] + b1v[2], acc[3][i] + b1v[3]};
      floatx4 p1 = {acc[4][i] + b1v[4], acc[5][i] + b1v[5], acc[6][i] + b1v[6], acc[7][i] + b1v[7]};
      *(floatx4*)(Asrc + (size_t)node * 128 + l16 * 8) = p0;
      *(floatx4*)(Asrc + (size_t)node * 128 + l16 * 8 + 4) = p1;
      floatx4 q0 = {acc[8][i], acc[9][i], acc[10][i], acc[11][i]};
      floatx4 q1 = {acc[12][i], acc[13][i], acc[14][i], acc[15][i]};
      *(floatx4*)(Adst + (size_t)node * 128 + l16 * 8) = q0;
      *(floatx4*)(Adst + (size_t)node * 128 + l16 * 8 + 4) = q1;
    }
  }

  // vector projections (exact f32)
  {
    int node = nb0 + (tid >> 2), sub = tid & 3;
    if (node < NN) {
      float vr[48];
      const float* vp = v + (size_t)node * 48;
#pragma unroll
      for (int j = 0; j < 48; j++) vr[j] = vp[j];
      for (int w = sub * 4; w < sub * 4 + 4; w++) {
        float bs0 = 0, bs1 = 0, bs2 = 0, bd0 = 0, bd1 = 0, bd2 = 0;
#pragma unroll
        for (int j = 0; j < 16; j++) {
          float w0 = wv[j * 16 + w], w1 = wv[(16 + j) * 16 + w];
          bs0 += vr[j * 3 + 0] * w0; bs1 += vr[j * 3 + 1] * w0; bs2 += vr[j * 3 + 2] * w0;
          bd0 += vr[j * 3 + 0] * w1; bd1 += vr[j * 3 + 1] * w1; bd2 += vr[j * 3 + 2] * w1;
        }
        size_t o = (size_t)node * 48 + w * 3;
        Bsrc[o + 0] = bs0; Bsrc[o + 1] = bs1; Bsrc[o + 2] = bs2;
        Bdst[o + 0] = bd0; Bdst[o + 1] = bd1; Bdst[o + 2] = bd2;
      }
    }
  }
}

// ---------------- edge message kernel (single-barrier) ----------------
// 64 edges/block, 256 threads, wave = 16 edges x 128 cols; all atomics at tail.
__global__ __launch_bounds__(256, 3) void gvp_edge(
    const int* __restrict__ eidx, const float* __restrict__ es,
    const float* __restrict__ ev, const short* __restrict__ w1et,
    const float* __restrict__ wlen, const short* __restrict__ w2t,
    const short* __restrict__ wgt, const float* __restrict__ Asrc,
    const float* __restrict__ Adst, const float* __restrict__ Bsrc,
    const float* __restrict__ Bdst, const float* __restrict__ b2,
    const float* __restrict__ wv, const float* __restrict__ bg,
    float* __restrict__ agg_s, float* __restrict__ agg_v) {
  __shared__ __align__(16) short lW2[128 * 136];   // 34816 B, stride 136 (2-way free)
  __shared__ __align__(16) short lh_all[4 * 16 * 136];  // 17408 B, per-wave regions
  __shared__ int lsrc[64];
  __shared__ int ldst[64];
  __shared__ float lev4[64][4];                    // x,y,z,len

  const int tid = threadIdx.x;
  const int wid = tid >> 6;
  const int lane = tid & 63;
  const int quad = lane >> 4;
  const int l16 = lane & 15;
  const int e0 = blockIdx.x * 64;

  if (tid < 64) lsrc[tid] = eidx[e0 + tid];
  else if (tid < 128) ldst[tid - 64] = eidx[NE + e0 + (tid - 64)];
  else if (tid < 192) {
    int er = tid & 63;
    const float* evp = ev + (size_t)(e0 + er) * 3;
    float x = evp[0], y = evp[1], z = evp[2];
    lev4[er][0] = x; lev4[er][1] = y; lev4[er][2] = z;
    lev4[er][3] = sqrtf(fmaxf(x * x + y * y + z * z, 1e-8f));
  }
#pragma unroll
  for (int i = 0; i < 8; i++) {  // stage W2 with stride 136
    int idx = tid + i * 256;
    int n = idx >> 4, q = idx & 15;
    *(intx4*)(lW2 + n * 136 + q * 8) = *(const intx4*)(w2t + n * 128 + q * 8);
  }
  __syncthreads();  // the only block barrier

  short* lh = lh_all + wid * 2176;

  // ---- GEMM1e: edge_s @ W1e (K=32, single MFMA chunk), A from global ----
  const int erow = wid * 16 + l16;
  const float* ep = es + (size_t)(e0 + erow) * 32 + quad * 8;
  floatx4 ea = *(const floatx4*)ep;
  floatx4 eb = *(const floatx4*)(ep + 4);
  shortx8 afrag;
#pragma unroll
  for (int j = 0; j < 4; j++) { afrag[j] = f2bf(ea[j]); afrag[4 + j] = f2bf(eb[j]); }
  floatx4 acc[8];
#pragma unroll
  for (int nt = 0; nt < 8; nt++) {
    shortx8 b = *(const shortx8*)(w1et + (nt * 16 + l16) * 32 + quad * 8);
    floatx4 z = {0.f, 0.f, 0.f, 0.f};
    acc[nt] = mfma16(afrag, b, z);
  }

  // ---- this lane's 4 edge rows ----
  int srcn[4], dstn[4];
  float lenr[4];
#pragma unroll
  for (int i = 0; i < 4; i++) {
    int r = wid * 16 + quad * 4 + i;
    srcn[i] = lsrc[r]; dstn[i] = ldst[r]; lenr[i] = lev4[r][3];
  }

  // ---- h += A_src[src] + A_dst[dst] (f32, vectorized via transposed layout) ----
#pragma unroll
  for (int i = 0; i < 4; i++) {
    const float* As = Asrc + (size_t)srcn[i] * 128 + l16 * 8;
    const float* Ad = Adst + (size_t)dstn[i] * 128 + l16 * 8;
    floatx4 s0 = *(const floatx4*)As, s1 = *(const floatx4*)(As + 4);
    floatx4 d0 = *(const floatx4*)Ad, d1 = *(const floatx4*)(Ad + 4);
    acc[0][i] += s0[0] + d0[0]; acc[1][i] += s0[1] + d0[1];
    acc[2][i] += s0[2] + d0[2]; acc[3][i] += s0[3] + d0[3];
    acc[4][i] += s1[0] + d1[0]; acc[5][i] += s1[1] + d1[1];
    acc[6][i] += s1[2] + d1[2]; acc[7][i] += s1[3] + d1[3];
  }
  // ---- h += len * wlen[col] ----
#pragma unroll
  for (int nt = 0; nt < 8; nt++) {
    float wl = wlen[nt * 16 + l16];
#pragma unroll
    for (int i = 0; i < 4; i++) acc[nt][i] += lenr[i] * wl;
  }

  // ---- silu -> per-wave lh (bf16) ----
#pragma unroll
  for (int nt = 0; nt < 8; nt++)
#pragma unroll
    for (int i = 0; i < 4; i++) {
      float h = acc[nt][i];
      lh[(quad * 4 + i) * 136 + nt * 16 + l16] = f2bf(h * sigm(h));
    }

  // ---- GEMM2: s2 = silu(h) @ W2 (K=128) ----
  floatx4 acc2[8] = {};
#pragma unroll
  for (int kc = 0; kc < 4; kc++) {
    shortx8 a = *(const shortx8*)(lh + l16 * 136 + kc * 32 + quad * 8);
#pragma unroll
    for (int nt = 0; nt < 8; nt++) {
      shortx8 b = *(const shortx8*)(lW2 + (nt * 16 + l16) * 136 + kc * 32 + quad * 8);
      acc2[nt] = mfma16(a, b, acc2[nt]);
    }
  }

  // ---- s2 = acc2 + b2; write bf16 to lh for gate GEMM ----
#pragma unroll
  for (int nt = 0; nt < 8; nt++) {
    float b2v = b2[nt * 16 + l16];
#pragma unroll
    for (int i = 0; i < 4; i++) {
      acc2[nt][i] += b2v;
      lh[(quad * 4 + i) * 136 + nt * 16 + l16] = f2bf(acc2[nt][i]);
    }
  }

  // ---- GEMM3: gate logits = s2 @ Wg (B-frags via L1 from global) ----
  floatx4 acc3 = {0.f, 0.f, 0.f, 0.f};
#pragma unroll
  for (int kc = 0; kc < 4; kc++) {
    shortx8 a = *(const shortx8*)(lh + l16 * 136 + kc * 32 + quad * 8);
    shortx8 b = *(const shortx8*)(wgt + l16 * 128 + kc * 32 + quad * 8);
    acc3 = mfma16(a, b, acc3);
  }

  // ---- vproj (exact f32) + gated agg_v atomics ----
  float wv32v = wv[32 * 16 + l16];
  float bgv = bg[l16];
#pragma unroll
  for (int i = 0; i < 4; i++) {
    int r = wid * 16 + quad * 4 + i;
    const float* Bs = Bsrc + (size_t)srcn[i] * 48 + l16 * 3;
    const float* Bd = Bdst + (size_t)dstn[i] * 48 + l16 * 3;
    float vx = Bs[0] + Bd[0] + lev4[r][0] * wv32v;
    float vy = Bs[1] + Bd[1] + lev4[r][1] * wv32v;
    float vz = Bs[2] + Bd[2] + lev4[r][2] * wv32v;
    float g = sigm(acc3[i] + bgv);
    float* ap = agg_v + (size_t)dstn[i] * 48 + l16 * 3;
    atomicAdd(ap + 0, g * vx);
    atomicAdd(ap + 1, g * vy);
    atomicAdd(ap + 2, g * vz);
  }
  // ---- agg_s atomics last: nothing waits on them ----
#pragma unroll
  for (int i = 0; i < 4; i++) {
    float* ap = agg_s + (size_t)dstn[i] * 128 + l16;
#pragma unroll
    for (int nt = 0; nt < 8; nt++) atomicAdd(ap + nt * 16, acc2[nt][i]);
  }
}

// ---------------- node update kernel (unchanged structure from R2) ----------------
__global__ __launch_bounds__(256) void gvp_node(
    const float* __restrict__ s, const float* __restrict__ v,
    const float* __restrict__ agg_s, const float* __restrict__ agg_v,
    const short* __restrict__ u1t, const short* __restrict__ u2t,
    const short* __restrict__ ugt, const float* __restrict__ b1,
    const float* __restrict__ b2, const float* __restrict__ uwv,
    const float* __restrict__ bg, const float* __restrict__ lng,
    const float* __restrict__ lnb, float* __restrict__ out_s,
    float* __restrict__ out_v) {
  __shared__ __align__(16) short lx[64 * 352];
  __shared__ __align__(16) short lw[128 * 32];
  const int tid = threadIdx.x;
  const int wid = tid >> 6;
  const int lane = tid & 63;
  const int quad = lane >> 4;
  const int l16 = lane & 15;
  const int nb0 = blockIdx.x * 64;

  intx4 z4 = {0, 0, 0, 0};
#pragma unroll
  for (int i = 0; i < 4; i++) {
    int idx = tid + i * 256;
    int r = idx >> 4, cc = (idx & 15) * 8;
    int node = nb0 + r;
    union { short sh[8]; intx4 v4; } u;
    u.v4 = z4;
    if (node < NN) {
      const float* sp = s + (size_t)node * 128 + cc;
      floatx4 f0 = *(const floatx4*)sp, f1 = *(const floatx4*)(sp + 4);
#pragma unroll
      for (int j = 0; j < 4; j++) { u.sh[j] = f2bf(f0[j]); u.sh[4 + j] = f2bf(f1[j]); }
    }
    *(intx4*)(lx + r * 288 + cc) = u.v4;
  }
#pragma unroll
  for (int i = 0; i < 4; i++) {
    int idx = tid + i * 256;
    int r = idx >> 4, cc = (idx & 15) * 8;
    int node = nb0 + r;
    union { short sh[8]; intx4 v4; } u;
    u.v4 = z4;
    if (node < NN) {
      const float* ap = agg_s + (size_t)node * 128 + cc;
      floatx4 f0 = *(const floatx4*)ap, f1 = *(const floatx4*)(ap + 4);
#pragma unroll
      for (int j = 0; j < 4; j++) { u.sh[j] = f2bf(f0[j]); u.sh[4 + j] = f2bf(f1[j]); }
    }
    *(intx4*)(lx + r * 288 + 128 + cc) = u.v4;
  }
  {
    int r = tid >> 2, p = tid & 3;
    int node = nb0 + r;
    int w0 = (p & 1) * 8;
    const float* vp = (p < 2) ? (v + (size_t)node * 48 + w0 * 3)
                              : (agg_v + (size_t)node * 48 + w0 * 3);
    int cbase = (p < 2) ? 256 : 272;
#pragma unroll
    for (int w = 0; w < 8; w++) {
      float nv = 0.f;
      if (node < NN) {
        float x = vp[w * 3], y = vp[w * 3 + 1], zz = vp[w * 3 + 2];
        nv = sqrtf(fmaxf(x * x + y * y + zz * zz, 1e-8f));
      }
      lx[r * 288 + cbase + w0 + w] = f2bf(nv);
    }
  }

  floatx4 acc[8] = {};
  for (int kc = 0; kc < 9; kc++) {
    __syncthreads();
#pragma unroll
    for (int i = 0; i < 2; i++) {
      int idx = tid + i * 256;
      int n = idx >> 2, q = idx & 3;
      *(intx4*)(lw + n * 32 + q * 8) = *(const intx4*)(u1t + (size_t)n * 288 + kc * 32 + q * 8);
    }
    __syncthreads();
    shortx8 a = *(const shortx8*)(lx + (wid * 16 + l16) * 288 + kc * 32 + quad * 8);
#pragma unroll
    for (int nt = 0; nt < 8; nt++) {
      shortx8 b = *(const shortx8*)(lw + (nt * 16 + l16) * 32 + quad * 8);
      acc[nt] = mfma16(a, b, acc[nt]);
    }
  }
  __syncthreads();
  short* lh = lx;
#pragma unroll
  for (int nt = 0; nt < 8; nt++)
#pragma unroll
    for (int i = 0; i < 4; i++) {
      int row = wid * 16 + quad * 4 + i;
      int col = nt * 16 + l16;
      float h = acc[nt][i] + b1[col];
      lh[row * 136 + col] = f2bf(h * sigm(h));
    }

  floatx4 acc2[8] = {};
  for (int kc = 0; kc < 4; kc++) {
    __syncthreads();
#pragma unroll
    for (int i = 0; i < 2; i++) {
      int idx = tid + i * 256;
      int n = idx >> 2, q = idx & 3;
      *(intx4*)(lw + n * 32 + q * 8) = *(const intx4*)(u2t + (size_t)n * 128 + kc * 32 + q * 8);
    }
    __syncthreads();
    shortx8 a = *(const shortx8*)(lh + (wid * 16 + l16) * 136 + kc * 32 + quad * 8);
#pragma unroll
    for (int nt = 0; nt < 8; nt++) {
      shortx8 b = *(const shortx8*)(lw + (nt * 16 + l16) * 32 + quad * 8);
      acc2[nt] = mfma16(a, b, acc2[nt]);
    }
  }
  __syncthreads();

#pragma unroll
  for (int nt = 0; nt < 8; nt++)
#pragma unroll
    for (int i = 0; i < 4; i++) {
      int row = wid * 16 + quad * 4 + i;
      int col = nt * 16 + l16;
      int node = nb0 + row;
      float ds = acc2[nt][i] + b2[col];
      lh[row * 136 + col] = f2bf(ds);
      float sv = (node < NN) ? s[(size_t)node * 128 + col] : 0.f;
      acc2[nt][i] = sv + ds;
    }

#pragma unroll
  for (int i = 0; i < 4; i++) {
    float sum = 0.f, sq = 0.f;
#pragma unroll
    for (int nt = 0; nt < 8; nt++) { float t = acc2[nt][i]; sum += t; sq += t * t; }
    for (int off = 1; off < 16; off <<= 1) {
      sum += __shfl_xor(sum, off);
      sq += __shfl_xor(sq, off);
    }
    float mean = sum * (1.f / 128.f);
    float var = sq * (1.f / 128.f) - mean * mean;
    float inv = rsqrtf(fmaxf(var, 0.f) + 1e-5f);
    int row = wid * 16 + quad * 4 + i;
    int node = nb0 + row;
    if (node < NN) {
#pragma unroll
      for (int nt = 0; nt < 8; nt++) {
        int col = nt * 16 + l16;
        float o = (acc2[nt][i] - mean) * inv * lng[col] + lnb[col];
        out_s[(size_t)node * 128 + col] = o;
      }
    }
  }
  __syncthreads();

  {
    int n = tid >> 4, q = tid & 15;
    *(intx4*)(lw + n * 128 + q * 8) = *(const intx4*)(ugt + n * 128 + q * 8);
  }
  float* lmvf = (float*)((char*)lx + 17408) + wid * 1600;
  {
    int e = lane >> 2, p = lane & 3;
    int node = nb0 + wid * 16 + e;
    const float* src = (p < 2) ? (v + (size_t)node * 48 + p * 24)
                               : (agg_v + (size_t)node * 48 + (p - 2) * 24);
    floatx4* dp = (floatx4*)(lmvf + e * 100 + p * 24);
    if (node < NN) {
      const floatx4* sp = (const floatx4*)src;
#pragma unroll
      for (int j = 0; j < 6; j++) dp[j] = sp[j];
    } else {
      floatx4 zf = {0.f, 0.f, 0.f, 0.f};
#pragma unroll
      for (int j = 0; j < 6; j++) dp[j] = zf;
    }
  }
  __syncthreads();

  floatx4 acc3 = {0.f, 0.f, 0.f, 0.f};
#pragma unroll
  for (int kc = 0; kc < 4; kc++) {
    shortx8 a = *(const shortx8*)(lh + (wid * 16 + l16) * 136 + kc * 32 + quad * 8);
    shortx8 b = *(const shortx8*)(lw + l16 * 128 + kc * 32 + quad * 8);
    acc3 = mfma16(a, b, acc3);
  }

  float vm[4][3] = {};
  for (int j = 0; j < 32; j++) {
    float wj = uwv[j * 16 + l16];
#pragma unroll
    for (int i = 0; i < 4; i++) {
      int e = quad * 4 + i;
      vm[i][0] += wj * lmvf[e * 100 + j * 3 + 0];
      vm[i][1] += wj * lmvf[e * 100 + j * 3 + 1];
      vm[i][2] += wj * lmvf[e * 100 + j * 3 + 2];
    }
  }
#pragma unroll
  for (int i = 0; i < 4; i++) {
    int row = wid * 16 + quad * 4 + i;
    int node = nb0 + row;
    if (node < NN) {
      float g = sigm(acc3[i] + bg[l16]);
      size_t base = (size_t)node * 48 + l16 * 3;
      out_v[base + 0] = v[base + 0] + g * vm[i][0];
      out_v[base + 1] = v[base + 1] + g * vm[i][1];
      out_v[base + 2] = v[base + 2] + g * vm[i][2];
    }
  }
}

extern "C" void kernel_launch(void* const* d_in, const int* in_sizes, int n_in,
                              void* d_out, int out_size, void* d_ws, size_t ws_size,
                              hipStream_t stream) {
  const float* s = (const float*)d_in[0];
  const float* v = (const float*)d_in[1];
  const int* eidx = (const int*)d_in[2];
  const float* es = (const float*)d_in[3];
  const float* ev = (const float*)d_in[4];
  const float* mW1 = (const float*)d_in[5];
  const float* mb1 = (const float*)d_in[6];
  const float* mW2 = (const float*)d_in[7];
  const float* mb2 = (const float*)d_in[8];
  const float* mWv = (const float*)d_in[9];
  const float* mWg = (const float*)d_in[10];
  const float* mbg = (const float*)d_in[11];
  const float* uW1 = (const float*)d_in[12];
  const float* ub1 = (const float*)d_in[13];
  const float* uW2 = (const float*)d_in[14];
  const float* ub2 = (const float*)d_in[15];
  const float* uWv = (const float*)d_in[16];
  const float* uWg = (const float*)d_in[17];
  const float* ubg = (const float*)d_in[18];
  const float* lng = (const float*)d_in[19];
  const float* lnb = (const float*)d_in[20];

  char* ws = (char*)d_ws;
  short* w1et = (short*)(ws + W1ET_OFF);
  float* wlen = (float*)(ws + WLEN_OFF);
  short* wcat = (short*)(ws + WCAT_OFF);
  short* w2t = (short*)(ws + W2T_OFF);
  short* wgt = (short*)(ws + WGT_OFF);
  short* u1t = (short*)(ws + U1T_OFF);
  short* u2t = (short*)(ws + U2T_OFF);
  short* ugt = (short*)(ws + UGT_OFF);
  float* Asrc = (float*)(ws + ASRC_OFF);
  float* Adst = (float*)(ws + ADST_OFF);
  float* Bsrc = (float*)(ws + BSRC_OFF);
  float* Bdst = (float*)(ws + BDST_OFF);
  float* agg_s = (float*)(ws + AGG_S_OFF);
  float* agg_v = (float*)(ws + AGG_V_OFF);

  hipMemsetAsync(ws + AGG_S_OFF, 0, AGG_BYTES, stream);
  gvp_prep<<<465, 256, 0, stream>>>(mW1, mW2, mWg, uW1, uW2, uWg,
                                    w1et, wlen, wcat, w2t, wgt, u1t, u2t, ugt);
  gvp_nodepre<<<(NN + 63) / 64, 256, 0, stream>>>(s, v, wcat, mb1, mWv,
                                                  Asrc, Adst, Bsrc, Bdst);
  gvp_edge<<<NE / 64, 256, 0, stream>>>(eidx, es, ev, w1et, wlen, w2t, wgt,
                                        Asrc, Adst, Bsrc, Bdst, mb2, mWv, mbg,
                                        agg_s, agg_v);
  gvp_node<<<(NN + 63) / 64, 256, 0, stream>>>(s, v, agg_s, agg_v, u1t, u2t, ugt,
                                               ub1, ub2, uWv, ubg, lng, lnb,
                                               (float*)d_out,
                                               (float*)d_out + (size_t)NN * 128);
}

// Round 4
// 592.819 us; speedup vs baseline: 1.4198x; 1.3338x over previous
//
#include <hip/hip_runtime.h>

typedef __attribute__((ext_vector_type(4))) float floatx4;
typedef __attribute__((ext_vector_type(8))) short shortx8;
typedef __attribute__((ext_vector_type(4))) short shortx4;
typedef __attribute__((ext_vector_type(4))) int intx4;
typedef __attribute__((ext_vector_type(2))) int intx2;

#define DEVI static __device__ __forceinline__

constexpr int NN = 20000;   // nodes
constexpr int NE = 640000;  // edges

// ---- workspace layout (bytes) ----
constexpr size_t W1ET_OFF = 0;                        // [128][32] bf16
constexpr size_t WLEN_OFF = 8192;                     // [128] f32
constexpr size_t WCAT_OFF = 8704;                     // [256][160] bf16
constexpr size_t W2T_OFF  = 90624;                    // [128][128] bf16
constexpr size_t WGT_OFF  = 123392;                   // [16][128] bf16
constexpr size_t U1T_OFF  = 127488;                   // [128][288] bf16
constexpr size_t U2T_OFF  = 201216;                   // [128][128] bf16
constexpr size_t UGT_OFF  = 233984;                   // [16][128] bf16
constexpr size_t ASRC_OFF = 238080;                   // [N][128] bf16 (col-transposed)
constexpr size_t ADST_OFF = ASRC_OFF + (size_t)NN * 128 * 2;
constexpr size_t BSRC_OFF = ADST_OFF + (size_t)NN * 128 * 2;   // [N][16][4] bf16 (xyz+pad)
constexpr size_t BDST_OFF = BSRC_OFF + (size_t)NN * 64 * 2;
constexpr size_t AGG_S_OFF = BDST_OFF + (size_t)NN * 64 * 2;   // [N][128] bf16
constexpr size_t AGG_V_OFF = AGG_S_OFF + (size_t)NN * 128 * 2; // [N][16][4] bf16
constexpr size_t AGG_BYTES = (size_t)NN * 128 * 2 + (size_t)NN * 64 * 2;

DEVI float bf2f(short h) {
  union { unsigned u; float f; } c;
  c.u = ((unsigned)(unsigned short)h) << 16;
  return c.f;
}
DEVI short f2bf(float f) {  // round-to-nearest-even
  union { float f; unsigned u; } c; c.f = f;
  unsigned x = c.u;
  return (short)((x + 0x7fffu + ((x >> 16) & 1u)) >> 16);
}
DEVI int pack2bf(float x, float y) {
  return (int)(unsigned short)f2bf(x) | ((int)(unsigned short)f2bf(y) << 16);
}
DEVI void atom_pk(short* addr, int val) {  // bf16x2 packed atomic add (RNE)
  asm volatile("global_atomic_pk_add_bf16 %0, %1, off" : : "v"(addr), "v"(val) : "memory");
}
DEVI float sigm(float x) { return 1.0f / (1.0f + __expf(-x)); }

DEVI floatx4 mfma16(shortx8 a, shortx8 b, floatx4 c) {
  return __builtin_amdgcn_mfma_f32_16x16x32_bf16(a, b, c, 0, 0, 0);
}

// ---------------- weight transform prep ----------------
// m_s_in: [s_src 0:128 | s_dst 128:256 | edge_s 256:288 | len 288 |
//          vn_src 289:305 | vn_dst 305:321 | len 321]
__global__ void gvp_prep(const float* __restrict__ mW1, const float* __restrict__ mW2,
                         const float* __restrict__ mWg, const float* __restrict__ uW1,
                         const float* __restrict__ uW2, const float* __restrict__ uWg,
                         short* __restrict__ w1et, float* __restrict__ wlen,
                         short* __restrict__ wcat, short* __restrict__ w2t,
                         short* __restrict__ wgt, short* __restrict__ u1t,
                         short* __restrict__ u2t, short* __restrict__ ugt) {
  int i = blockIdx.x * 256 + threadIdx.x;
  if (i < 4096) { int n = i >> 5, k = i & 31; w1et[i] = f2bf(mW1[(256 + k) * 128 + n]); return; }
  i -= 4096;
  if (i < 128) { wlen[i] = mW1[288 * 128 + i] + mW1[321 * 128 + i]; return; }
  i -= 128;
  if (i < 40960) {  // wcat [256][160]
    int n = i / 160, k = i % 160;
    float val = 0.f;
    if (n < 128) {
      if (k < 128) val = mW1[k * 128 + n];
      else if (k < 144) val = mW1[(161 + k) * 128 + n];   // 289 + (k-128)
    } else {
      int n2 = n - 128;
      if (k < 128) val = mW1[(128 + k) * 128 + n2];
      else if (k < 144) val = mW1[(177 + k) * 128 + n2];  // 305 + (k-128)
    }
    wcat[i] = f2bf(val);
    return;
  }
  i -= 40960;
  if (i < 16384) { int n = i >> 7, k = i & 127; w2t[i] = f2bf(mW2[k * 128 + n]); return; }
  i -= 16384;
  if (i < 2048) { int g = i >> 7, k = i & 127; wgt[i] = f2bf(mWg[k * 16 + g]); return; }
  i -= 2048;
  if (i < 36864) { int n = i / 288, k = i % 288; u1t[i] = f2bf(uW1[k * 128 + n]); return; }
  i -= 36864;
  if (i < 16384) { int n = i >> 7, k = i & 127; u2t[i] = f2bf(uW2[k * 128 + n]); return; }
  i -= 16384;
  if (i < 2048) { int g = i >> 7, k = i & 127; ugt[i] = f2bf(uWg[k * 16 + g]); return; }
}

// ---------------- per-node precompute ----------------
// A_src = [s,vn]@W1a + b1, A_dst = [s,vn]@W1b stored bf16 col-transposed
// (A[node][l16*8+t] = col t*16+l16). B_src/B_dst bf16 [node][16][4] (xyz,pad).
__global__ __launch_bounds__(256) void gvp_nodepre(
    const float* __restrict__ s, const float* __restrict__ v,
    const short* __restrict__ wcat, const float* __restrict__ b1,
    const float* __restrict__ wv, short* __restrict__ Asrc,
    short* __restrict__ Adst, short* __restrict__ Bsrc, short* __restrict__ Bdst) {
  __shared__ __align__(16) short lx[64 * 160];
  const int tid = threadIdx.x;
  const int wid = tid >> 6;
  const int lane = tid & 63;
  const int quad = lane >> 4;
  const int l16 = lane & 15;
  const int nb0 = blockIdx.x * 64;

  intx4 z4 = {0, 0, 0, 0};
#pragma unroll
  for (int i = 0; i < 4; i++) {
    int idx = tid + i * 256;
    int r = idx >> 4, cc = (idx & 15) * 8;
    int node = nb0 + r;
    union { short sh[8]; intx4 v4; } u;
    u.v4 = z4;
    if (node < NN) {
      const float* sp = s + (size_t)node * 128 + cc;
      floatx4 f0 = *(const floatx4*)sp, f1 = *(const floatx4*)(sp + 4);
#pragma unroll
      for (int j = 0; j < 4; j++) { u.sh[j] = f2bf(f0[j]); u.sh[4 + j] = f2bf(f1[j]); }
    }
    *(intx4*)(lx + r * 160 + cc) = u.v4;
  }
  if (tid < 64) {
    int node = nb0 + tid;
    union { short sh[16]; intx4 v4[2]; } u;
#pragma unroll
    for (int j = 0; j < 16; j++) {
      float nv = 0.f;
      if (node < NN) {
        const float* vp = v + (size_t)node * 48 + j * 3;
        nv = sqrtf(fmaxf(vp[0] * vp[0] + vp[1] * vp[1] + vp[2] * vp[2], 1e-8f));
      }
      u.sh[j] = f2bf(nv);
    }
    *(intx4*)(lx + tid * 160 + 128) = u.v4[0];
    *(intx4*)(lx + tid * 160 + 136) = u.v4[1];
    *(intx4*)(lx + tid * 160 + 144) = z4;
    *(intx4*)(lx + tid * 160 + 152) = z4;
  }
  __syncthreads();  // only barrier

  floatx4 acc[16] = {};
#pragma unroll
  for (int kc = 0; kc < 5; kc++) {
    shortx8 a = *(const shortx8*)(lx + (wid * 16 + l16) * 160 + kc * 32 + quad * 8);
#pragma unroll
    for (int nt = 0; nt < 16; nt++) {
      shortx8 b = *(const shortx8*)(wcat + (size_t)(nt * 16 + l16) * 160 + kc * 32 + quad * 8);
      acc[nt] = mfma16(a, b, acc[nt]);
    }
  }

  float b1v[8];
#pragma unroll
  for (int nt = 0; nt < 8; nt++) b1v[nt] = b1[nt * 16 + l16];
#pragma unroll
  for (int i = 0; i < 4; i++) {
    int row = wid * 16 + quad * 4 + i;
    int node = nb0 + row;
    if (node < NN) {
      union { short sh[8]; intx4 v4; } us, ud;
#pragma unroll
      for (int nt = 0; nt < 8; nt++) {
        us.sh[nt] = f2bf(acc[nt][i] + b1v[nt]);
        ud.sh[nt] = f2bf(acc[8 + nt][i]);
      }
      *(intx4*)(Asrc + (size_t)node * 128 + l16 * 8) = us.v4;
      *(intx4*)(Adst + (size_t)node * 128 + l16 * 8) = ud.v4;
    }
  }

  // vector projections (f32 math, bf16 store)
  {
    int node = nb0 + (tid >> 2), sub = tid & 3;
    if (node < NN) {
      float vr[48];
      const float* vp = v + (size_t)node * 48;
#pragma unroll
      for (int j = 0; j < 48; j++) vr[j] = vp[j];
      for (int w = sub * 4; w < sub * 4 + 4; w++) {
        float bs0 = 0, bs1 = 0, bs2 = 0, bd0 = 0, bd1 = 0, bd2 = 0;
#pragma unroll
        for (int j = 0; j < 16; j++) {
          float w0 = wv[j * 16 + w], w1 = wv[(16 + j) * 16 + w];
          bs0 += vr[j * 3 + 0] * w0; bs1 += vr[j * 3 + 1] * w0; bs2 += vr[j * 3 + 2] * w0;
          bd0 += vr[j * 3 + 0] * w1; bd1 += vr[j * 3 + 1] * w1; bd2 += vr[j * 3 + 2] * w1;
        }
        union { short sh[4]; intx2 v2; } ub, ud2;
        ub.sh[0] = f2bf(bs0); ub.sh[1] = f2bf(bs1); ub.sh[2] = f2bf(bs2); ub.sh[3] = 0;
        ud2.sh[0] = f2bf(bd0); ud2.sh[1] = f2bf(bd1); ud2.sh[2] = f2bf(bd2); ud2.sh[3] = 0;
        *(intx2*)(Bsrc + (size_t)node * 64 + w * 4) = ub.v2;
        *(intx2*)(Bdst + (size_t)node * 64 + w * 4) = ud2.v2;
      }
    }
  }
}

// ---------------- edge message kernel ----------------
// 64 edges/block, 256 threads; single barrier; bf16 packed atomics at tail.
__global__ __launch_bounds__(256, 5) void gvp_edge(
    const int* __restrict__ eidx, const float* __restrict__ es,
    const float* __restrict__ ev, const short* __restrict__ w1et,
    const float* __restrict__ wlen, const short* __restrict__ w2t,
    const short* __restrict__ wgt, const short* __restrict__ Asrc,
    const short* __restrict__ Adst, const short* __restrict__ Bsrc,
    const short* __restrict__ Bdst, const float* __restrict__ b2,
    const float* __restrict__ wv, const float* __restrict__ bg,
    short* __restrict__ agg_s, short* __restrict__ agg_v) {
  __shared__ __align__(16) short lh_all[4 * 16 * 136];  // per-wave s2/silu tiles
  __shared__ int lsrc[64];
  __shared__ int ldst[64];
  __shared__ float lev4[64][4];  // x,y,z,len

  const int tid = threadIdx.x;
  const int wid = tid >> 6;
  const int lane = tid & 63;
  const int quad = lane >> 4;
  const int l16 = lane & 15;
  const int e0 = blockIdx.x * 64;

  if (tid < 64) lsrc[tid] = eidx[e0 + tid];
  else if (tid < 128) ldst[tid - 64] = eidx[NE + e0 + (tid - 64)];
  else if (tid < 192) {
    int er = tid & 63;
    const float* evp = ev + (size_t)(e0 + er) * 3;
    float x = evp[0], y = evp[1], z = evp[2];
    lev4[er][0] = x; lev4[er][1] = y; lev4[er][2] = z;
    lev4[er][3] = sqrtf(fmaxf(x * x + y * y + z * z, 1e-8f));
  }
  __syncthreads();  // the only block barrier

  short* lh = lh_all + wid * 2176;

  // ---- GEMM1e: edge_s @ W1e (K=32), B-frags from global (L1-hot) ----
  const int erow = wid * 16 + l16;
  const float* ep = es + (size_t)(e0 + erow) * 32 + quad * 8;
  floatx4 ea = *(const floatx4*)ep;
  floatx4 eb = *(const floatx4*)(ep + 4);
  shortx8 afrag;
#pragma unroll
  for (int j = 0; j < 4; j++) { afrag[j] = f2bf(ea[j]); afrag[4 + j] = f2bf(eb[j]); }
  floatx4 acc[8];
#pragma unroll
  for (int nt = 0; nt < 8; nt++) {
    shortx8 b = *(const shortx8*)(w1et + (nt * 16 + l16) * 32 + quad * 8);
    floatx4 z = {0.f, 0.f, 0.f, 0.f};
    acc[nt] = mfma16(afrag, b, z);
  }

  // ---- this lane's 4 edge rows ----
  int srcn[4], dstn[4];
  float lenr[4];
#pragma unroll
  for (int i = 0; i < 4; i++) {
    int r = wid * 16 + quad * 4 + i;
    srcn[i] = lsrc[r]; dstn[i] = ldst[r]; lenr[i] = lev4[r][3];
  }

  // ---- h += A_src[src] + A_dst[dst] (bf16 gathers, f32 add) ----
#pragma unroll
  for (int i = 0; i < 4; i++) {
    shortx8 s8 = *(const shortx8*)(Asrc + (size_t)srcn[i] * 128 + l16 * 8);
    shortx8 d8 = *(const shortx8*)(Adst + (size_t)dstn[i] * 128 + l16 * 8);
#pragma unroll
    for (int nt = 0; nt < 8; nt++) acc[nt][i] += bf2f(s8[nt]) + bf2f(d8[nt]);
  }
  // ---- h += len * wlen[col] ----
#pragma unroll
  for (int nt = 0; nt < 8; nt++) {
    float wl = wlen[nt * 16 + l16];
#pragma unroll
    for (int i = 0; i < 4; i++) acc[nt][i] += lenr[i] * wl;
  }

  // ---- silu -> per-wave lh (bf16) ----
#pragma unroll
  for (int nt = 0; nt < 8; nt++)
#pragma unroll
    for (int i = 0; i < 4; i++) {
      float h = acc[nt][i];
      lh[(quad * 4 + i) * 136 + nt * 16 + l16] = f2bf(h * sigm(h));
    }

  // ---- GEMM2: s2 = silu(h) @ W2 (K=128), B-frags from global ----
  floatx4 acc2[8] = {};
#pragma unroll
  for (int kc = 0; kc < 4; kc++) {
    shortx8 a = *(const shortx8*)(lh + l16 * 136 + kc * 32 + quad * 8);
#pragma unroll
    for (int nt = 0; nt < 8; nt++) {
      shortx8 b = *(const shortx8*)(w2t + (size_t)(nt * 16 + l16) * 128 + kc * 32 + quad * 8);
      acc2[nt] = mfma16(a, b, acc2[nt]);
    }
  }

  // ---- s2 = acc2 + b2 -> lh bf16 (gate GEMM input + atomic source) ----
#pragma unroll
  for (int nt = 0; nt < 8; nt++) {
    float b2v = b2[nt * 16 + l16];
#pragma unroll
    for (int i = 0; i < 4; i++)
      lh[(quad * 4 + i) * 136 + nt * 16 + l16] = f2bf(acc2[nt][i] + b2v);
  }

  // ---- GEMM3: gate logits = s2 @ Wg ----
  floatx4 acc3 = {0.f, 0.f, 0.f, 0.f};
#pragma unroll
  for (int kc = 0; kc < 4; kc++) {
    shortx8 a = *(const shortx8*)(lh + l16 * 136 + kc * 32 + quad * 8);
    shortx8 b = *(const shortx8*)(wgt + l16 * 128 + kc * 32 + quad * 8);
    acc3 = mfma16(a, b, acc3);
  }

  // ---- vproj (bf16 gathers) + gated packed agg_v atomics ----
  float wv32v = wv[32 * 16 + l16];
  float bgv = bg[l16];
#pragma unroll
  for (int i = 0; i < 4; i++) {
    int r = wid * 16 + quad * 4 + i;
    shortx4 bs = *(const shortx4*)(Bsrc + (size_t)srcn[i] * 64 + l16 * 4);
    shortx4 bd = *(const shortx4*)(Bdst + (size_t)dstn[i] * 64 + l16 * 4);
    float vx = bf2f(bs[0]) + bf2f(bd[0]) + lev4[r][0] * wv32v;
    float vy = bf2f(bs[1]) + bf2f(bd[1]) + lev4[r][1] * wv32v;
    float vz = bf2f(bs[2]) + bf2f(bd[2]) + lev4[r][2] * wv32v;
    float g = sigm(acc3[i] + bgv);
    short* ap = agg_v + (size_t)dstn[i] * 64 + l16 * 4;
    atom_pk(ap, pack2bf(g * vx, g * vy));
    atom_pk(ap + 2, pack2bf(g * vz, 0.f));
  }

  // ---- agg_s packed atomics: re-read s2 pairs from lh ----
#pragma unroll 4
  for (int i = 0; i < 16; i++) {
    int d = ldst[wid * 16 + i];
    int val = *(const int*)(lh + i * 136 + 2 * lane);
    atom_pk(agg_s + (size_t)d * 128 + 2 * lane, val);
  }
}

// ---------------- node update kernel (2 barriers) ----------------
__global__ __launch_bounds__(256) void gvp_node(
    const float* __restrict__ s, const float* __restrict__ v,
    const short* __restrict__ agg_s, const short* __restrict__ agg_v,
    const short* __restrict__ u1t, const short* __restrict__ u2t,
    const short* __restrict__ ugt, const float* __restrict__ b1,
    const float* __restrict__ b2, const float* __restrict__ uwv,
    const float* __restrict__ bg, const float* __restrict__ lng,
    const float* __restrict__ lnb, float* __restrict__ out_s,
    float* __restrict__ out_v) {
  __shared__ __align__(16) short lx[64 * 352];  // X2 [64][288]; overlays: lh, lmvf
  const int tid = threadIdx.x;
  const int wid = tid >> 6;
  const int lane = tid & 63;
  const int quad = lane >> 4;
  const int l16 = lane & 15;
  const int nb0 = blockIdx.x * 64;

  intx4 z4 = {0, 0, 0, 0};
#pragma unroll
  for (int i = 0; i < 4; i++) {
    int idx = tid + i * 256;
    int r = idx >> 4, cc = (idx & 15) * 8;
    int node = nb0 + r;
    union { short sh[8]; intx4 v4; } u;
    u.v4 = z4;
    if (node < NN) {
      const float* sp = s + (size_t)node * 128 + cc;
      floatx4 f0 = *(const floatx4*)sp, f1 = *(const floatx4*)(sp + 4);
#pragma unroll
      for (int j = 0; j < 4; j++) { u.sh[j] = f2bf(f0[j]); u.sh[4 + j] = f2bf(f1[j]); }
    }
    *(intx4*)(lx + r * 288 + cc) = u.v4;
  }
#pragma unroll
  for (int i = 0; i < 4; i++) {  // agg_s: already bf16, straight copy
    int idx = tid + i * 256;
    int r = idx >> 4, cc = (idx & 15) * 8;
    int node = nb0 + r;
    intx4 val = z4;
    if (node < NN) val = *(const intx4*)(agg_s + (size_t)node * 128 + cc);
    *(intx4*)(lx + r * 288 + 128 + cc) = val;
  }
  {
    int r = tid >> 2, p = tid & 3;
    int node = nb0 + r;
    int w0 = (p & 1) * 8;
    if (p < 2) {
#pragma unroll
      for (int w = 0; w < 8; w++) {
        float nv = 0.f;
        if (node < NN) {
          const float* vp = v + (size_t)node * 48 + (w0 + w) * 3;
          nv = sqrtf(fmaxf(vp[0] * vp[0] + vp[1] * vp[1] + vp[2] * vp[2], 1e-8f));
        }
        lx[r * 288 + 256 + w0 + w] = f2bf(nv);
      }
    } else {
#pragma unroll
      for (int w = 0; w < 8; w++) {
        float nv = 0.f;
        if (node < NN) {
          const short* ap = agg_v + (size_t)node * 64 + (w0 + w) * 4;
          float x = bf2f(ap[0]), y = bf2f(ap[1]), zz = bf2f(ap[2]);
          nv = sqrtf(fmaxf(x * x + y * y + zz * zz, 1e-8f));
        }
        lx[r * 288 + 272 + w0 + w] = f2bf(nv);
      }
    }
  }
  __syncthreads();  // X2 ready

  // ---- GEMM1 (K=288), B-frags from global u1t ----
  floatx4 acc[8] = {};
#pragma unroll
  for (int kc = 0; kc < 9; kc++) {
    shortx8 a = *(const shortx8*)(lx + (wid * 16 + l16) * 288 + kc * 32 + quad * 8);
#pragma unroll
    for (int nt = 0; nt < 8; nt++) {
      shortx8 b = *(const shortx8*)(u1t + (size_t)(nt * 16 + l16) * 288 + kc * 32 + quad * 8);
      acc[nt] = mfma16(a, b, acc[nt]);
    }
  }
  __syncthreads();  // X2 dead; safe to overlay lh/lmvf

  short* lh = lx;  // [64][136] bf16
#pragma unroll
  for (int nt = 0; nt < 8; nt++)
#pragma unroll
    for (int i = 0; i < 4; i++) {
      int row = wid * 16 + quad * 4 + i;
      float h = acc[nt][i] + b1[nt * 16 + l16];
      lh[row * 136 + nt * 16 + l16] = f2bf(h * sigm(h));
    }

  // ---- GEMM2 (K=128), B from global u2t ----
  floatx4 acc2[8] = {};
#pragma unroll
  for (int kc = 0; kc < 4; kc++) {
    shortx8 a = *(const shortx8*)(lh + (wid * 16 + l16) * 136 + kc * 32 + quad * 8);
#pragma unroll
    for (int nt = 0; nt < 8; nt++) {
      shortx8 b = *(const shortx8*)(u2t + (size_t)(nt * 16 + l16) * 128 + kc * 32 + quad * 8);
      acc2[nt] = mfma16(a, b, acc2[nt]);
    }
  }

  // ---- epilogue: ds -> lh (gate input); t = s + ds in acc2 ----
#pragma unroll
  for (int nt = 0; nt < 8; nt++)
#pragma unroll
    for (int i = 0; i < 4; i++) {
      int row = wid * 16 + quad * 4 + i;
      int col = nt * 16 + l16;
      int node = nb0 + row;
      float ds = acc2[nt][i] + b2[col];
      lh[row * 136 + col] = f2bf(ds);
      float sv = (node < NN) ? s[(size_t)node * 128 + col] : 0.f;
      acc2[nt][i] = sv + ds;
    }

  // ---- LayerNorm + out_s store ----
#pragma unroll
  for (int i = 0; i < 4; i++) {
    float sum = 0.f, sq = 0.f;
#pragma unroll
    for (int nt = 0; nt < 8; nt++) { float t = acc2[nt][i]; sum += t; sq += t * t; }
    for (int off = 1; off < 16; off <<= 1) {
      sum += __shfl_xor(sum, off);
      sq += __shfl_xor(sq, off);
    }
    float mean = sum * (1.f / 128.f);
    float var = sq * (1.f / 128.f) - mean * mean;
    float inv = rsqrtf(fmaxf(var, 0.f) + 1e-5f);
    int node = nb0 + wid * 16 + quad * 4 + i;
    if (node < NN) {
#pragma unroll
      for (int nt = 0; nt < 8; nt++) {
        int col = nt * 16 + l16;
        float o = (acc2[nt][i] - mean) * inv * lng[col] + lnb[col];
        out_s[(size_t)node * 128 + col] = o;
      }
    }
  }

  // ---- per-wave u_v_in tile [16][100] f32 (overlay past lh) ----
  float* lmvf = (float*)((char*)lx + 17408) + wid * 1600;
  {
    int e = lane >> 2, p = lane & 3;
    int node = nb0 + wid * 16 + e;
    if (p < 2) {
      floatx4* dp = (floatx4*)(lmvf + e * 100 + p * 24);
      if (node < NN) {
        const floatx4* sp = (const floatx4*)(v + (size_t)node * 48 + p * 24);
#pragma unroll
        for (int j = 0; j < 6; j++) dp[j] = sp[j];
      } else {
        floatx4 zf = {0.f, 0.f, 0.f, 0.f};
#pragma unroll
        for (int j = 0; j < 6; j++) dp[j] = zf;
      }
    } else {
      int wbase = (p - 2) * 8;
#pragma unroll
      for (int w = 0; w < 8; w++) {
        float x = 0.f, y = 0.f, zz = 0.f;
        if (node < NN) {
          const short* ap = agg_v + (size_t)node * 64 + (wbase + w) * 4;
          x = bf2f(ap[0]); y = bf2f(ap[1]); zz = bf2f(ap[2]);
        }
        float* dp = lmvf + e * 100 + 48 + (wbase + w) * 3;
        dp[0] = x; dp[1] = y; dp[2] = zz;
      }
    }
  }

  // ---- GEMM3: gate logits = ds @ Ug (B from global) ----
  floatx4 acc3 = {0.f, 0.f, 0.f, 0.f};
#pragma unroll
  for (int kc = 0; kc < 4; kc++) {
    shortx8 a = *(const shortx8*)(lh + (wid * 16 + l16) * 136 + kc * 32 + quad * 8);
    shortx8 b = *(const shortx8*)(ugt + l16 * 128 + kc * 32 + quad * 8);
    acc3 = mfma16(a, b, acc3);
  }

  // ---- dv + residual store ----
  float vm[4][3] = {};
  for (int j = 0; j < 32; j++) {
    float wj = uwv[j * 16 + l16];
#pragma unroll
    for (int i = 0; i < 4; i++) {
      int e = quad * 4 + i;
      vm[i][0] += wj * lmvf[e * 100 + j * 3 + 0];
      vm[i][1] += wj * lmvf[e * 100 + j * 3 + 1];
      vm[i][2] += wj * lmvf[e * 100 + j * 3 + 2];
    }
  }
#pragma unroll
  for (int i = 0; i < 4; i++) {
    int node = nb0 + wid * 16 + quad * 4 + i;
    if (node < NN) {
      float g = sigm(acc3[i] + bg[l16]);
      size_t base = (size_t)node * 48 + l16 * 3;
      out_v[base + 0] = v[base + 0] + g * vm[i][0];
      out_v[base + 1] = v[base + 1] + g * vm[i][1];
      out_v[base + 2] = v[base + 2] + g * vm[i][2];
    }
  }
}

extern "C" void kernel_launch(void* const* d_in, const int* in_sizes, int n_in,
                              void* d_out, int out_size, void* d_ws, size_t ws_size,
                              hipStream_t stream) {
  const float* s = (const float*)d_in[0];
  const float* v = (const float*)d_in[1];
  const int* eidx = (const int*)d_in[2];
  const float* es = (const float*)d_in[3];
  const float* ev = (const float*)d_in[4];
  const float* mW1 = (const float*)d_in[5];
  const float* mb1 = (const float*)d_in[6];
  const float* mW2 = (const float*)d_in[7];
  const float* mb2 = (const float*)d_in[8];
  const float* mWv = (const float*)d_in[9];
  const float* mWg = (const float*)d_in[10];
  const float* mbg = (const float*)d_in[11];
  const float* uW1 = (const float*)d_in[12];
  const float* ub1 = (const float*)d_in[13];
  const float* uW2 = (const float*)d_in[14];
  const float* ub2 = (const float*)d_in[15];
  const float* uWv = (const float*)d_in[16];
  const float* uWg = (const float*)d_in[17];
  const float* ubg = (const float*)d_in[18];
  const float* lng = (const float*)d_in[19];
  const float* lnb = (const float*)d_in[20];

  char* ws = (char*)d_ws;
  short* w1et = (short*)(ws + W1ET_OFF);
  float* wlen = (float*)(ws + WLEN_OFF);
  short* wcat = (short*)(ws + WCAT_OFF);
  short* w2t = (short*)(ws + W2T_OFF);
  short* wgt = (short*)(ws + WGT_OFF);
  short* u1t = (short*)(ws + U1T_OFF);
  short* u2t = (short*)(ws + U2T_OFF);
  short* ugt = (short*)(ws + UGT_OFF);
  short* Asrc = (short*)(ws + ASRC_OFF);
  short* Adst = (short*)(ws + ADST_OFF);
  short* Bsrc = (short*)(ws + BSRC_OFF);
  short* Bdst = (short*)(ws + BDST_OFF);
  short* agg_s = (short*)(ws + AGG_S_OFF);
  short* agg_v = (short*)(ws + AGG_V_OFF);

  hipMemsetAsync(ws + AGG_S_OFF, 0, AGG_BYTES, stream);
  gvp_prep<<<465, 256, 0, stream>>>(mW1, mW2, mWg, uW1, uW2, uWg,
                                    w1et, wlen, wcat, w2t, wgt, u1t, u2t, ugt);
  gvp_nodepre<<<(NN + 63) / 64, 256, 0, stream>>>(s, v, wcat, mb1, mWv,
                                                  Asrc, Adst, Bsrc, Bdst);
  gvp_edge<<<NE / 64, 256, 0, stream>>>(eidx, es, ev, w1et, wlen, w2t, wgt,
                                        Asrc, Adst, Bsrc, Bdst, mb2, mWv, mbg,
                                        agg_s, agg_v);
  gvp_node<<<(NN + 63) / 64, 256, 0, stream>>>(s, v, agg_s, agg_v, u1t, u2t, ugt,
                                               ub1, ub2, uWv, ubg, lng, lnb,
                                               (float*)d_out,
                                               (float*)d_out + (size_t)NN * 128);
}